// Round 13
// baseline (623.057 us; speedup 1.0000x reference)
//
#include <hip/hip_runtime.h>
#include <stdint.h>

typedef unsigned long long u64;
typedef unsigned int u32;
typedef unsigned short u16;
typedef u32 u32x4 __attribute__((ext_vector_type(4)));
typedef float f32x4 __attribute__((ext_vector_type(4)));

// Fixed problem shape (N=100000, E=1600000, C_IN=C_OUT=128, NHEADS=4)
#define CIN 128
#define NN 100000
#define EE 1600000
#define N4 (NN * 4)
#define EK_OFF (NN * CIN)          // 12,800,000 f32
#define NM_OFF (EK_OFF + EE)       // 14,400,000
#define SL_OFF (NM_OFF + NN)       // 14,500,000
#define GRID 1024                  // 4 blocks/CU x 256 CUs -> co-resident by construction
#define BLK 256

__device__ __forceinline__ float bf2f(u16 v) {
    union { u32 u; float f; } cv;
    cv.u = ((u32)v) << 16;
    return cv.f;
}

__device__ __forceinline__ u16 f2bf(float f) {      // RNE f32 -> bf16
    u32 b = __float_as_uint(f);
    return (u16)((b + 0x7FFFu + ((b >> 16) & 1u)) >> 16);
}

// Monotonic map: f32 -> u32 preserving total order. Never 0 for finite input,
// so key==0 means "empty slot".
__device__ __forceinline__ u32 mono32(float f) {
    u32 u = __float_as_uint(f);
    return ((int)u >= 0) ? (u | 0x80000000u) : ~u;
}

// Soft grid barrier: cumulative counter, one arrival per block. Agent-scope
// release RMW (emits L2 writeback on gfx950) + acquire fence after the spin
// (L2 invalidate) give cross-XCD visibility — same mechanism grid.sync()
// uses. Co-residency guaranteed: GRID=1024 = 256 CUs x 4 blocks/CU
// (launch_bounds(256,4) caps VGPR at 128, LDS 4KB). Bounded spin turns any
// surprise into a clean numeric failure instead of a hang.
__device__ __forceinline__ void grid_barrier(u32* bar, u32 target) {
    __syncthreads();
    if (threadIdx.x == 0) {
        __threadfence();   // release: write back dirty L2 (agent scope)
        __hip_atomic_fetch_add(bar, 1u, __ATOMIC_ACQ_REL, __HIP_MEMORY_SCOPE_AGENT);
        int spins = 0;
        while (__hip_atomic_load(bar, __ATOMIC_RELAXED, __HIP_MEMORY_SCOPE_AGENT) < target) {
            __builtin_amdgcn_s_sleep(8);
            if (++spins > (1 << 22)) break;   // failsafe ~<1s, then clean numeric fail
        }
        __threadfence();   // acquire: invalidate L1/L2 so post-barrier reads are fresh
    }
    __syncthreads();
}

// ---------------------------------------------------------------------------
// One kernel, 4 phases, 3 soft barriers. Zero-fills (x_out, seg, nm, bar) are
// done by hipMemsetAsync before launch.
//  P1: V table (LDS) + s-tables (bf16x4)          [r11 k_s core]
//  P2: fused segmax+argmin, test-then-atomic       [r11 k_edge]
//  P3: decode winners -> node_mask                 [r11 k_select]
//  P4: edge_keep + node_mask f32 + slices          [r11 k_final]
__global__ __launch_bounds__(256, 4) void k_fused(const u16* __restrict__ x,
                                                  const int* __restrict__ ei,
                                                  const int* __restrict__ sl,
                                                  const u16* __restrict__ W,
                                                  const u16* __restrict__ att,
                                                  float* __restrict__ out,
                                                  ushort4* __restrict__ sjb,
                                                  ushort4* __restrict__ sib,
                                                  int* __restrict__ nm,
                                                  u64* __restrict__ seg,
                                                  u32* __restrict__ bar) {
    const int stride = GRID * BLK;
    const int tid = blockIdx.x * BLK + threadIdx.x;

    // ---------------- phase 1: V table + s-tables ----------------
    __shared__ float Vl[1024];
    for (int slot = threadIdx.x; slot < 1024; slot += BLK) {
        int k = slot >> 3, h8 = slot & 7;
        int head = h8 & 3;
        int off = (h8 < 4) ? 0 : 32;
        float acc = 0.0f;
        #pragma unroll
        for (int c = 0; c < 32; ++c)
            acc += bf2f(W[k * CIN + head * 32 + c]) * bf2f(att[head * 64 + off + c]);
        Vl[slot] = acc;
    }
    __syncthreads();
    for (int n = tid; n < NN; n += stride) {
        const uint4* row = (const uint4*)(x + (size_t)n * CIN);
        float acc[8];
        #pragma unroll
        for (int h = 0; h < 8; ++h) acc[h] = 0.0f;
        #pragma unroll 4
        for (int q = 0; q < 16; ++q) {
            uint4 v = row[q];
            u32 w[4] = { v.x, v.y, v.z, v.w };
            #pragma unroll
            for (int j = 0; j < 4; ++j) {
                float x0 = bf2f((u16)(w[j] & 0xFFFFu));
                float x1 = bf2f((u16)(w[j] >> 16));
                int k0 = q * 8 + j * 2;
                #pragma unroll
                for (int h = 0; h < 8; ++h) acc[h] += x0 * Vl[k0 * 8 + h];
                #pragma unroll
                for (int h = 0; h < 8; ++h) acc[h] += x1 * Vl[(k0 + 1) * 8 + h];
            }
        }
        ushort4 a, b;
        a.x = f2bf(acc[0]); a.y = f2bf(acc[1]); a.z = f2bf(acc[2]); a.w = f2bf(acc[3]);
        b.x = f2bf(acc[4]); b.y = f2bf(acc[5]); b.z = f2bf(acc[6]); b.w = f2bf(acc[7]);
        sjb[n] = a;
        sib[n] = b;
    }

    grid_barrier(bar, 1 * GRID);

    // ---------------- phase 2: fused argmax (test-then-atomic) ----------------
    // key=(mono32(alpha)<<32)|~e: max score, tie -> min edge id. Stale test
    // reads are only ever smaller -> extra atomic at worst (seg monotone).
    for (int e = tid; e < EE; e += stride) {
        int src = ei[e], dst = ei[EE + e];
        ushort4 sj = sjb[src];
        ushort4 si = sib[dst];
        u64 lo = (u64)(u32)(~(u32)e);
        u64* slot = seg + (size_t)src * 4;
        ulonglong2 c01 = *(const ulonglong2*)(slot);
        ulonglong2 c23 = *(const ulonglong2*)(slot + 2);
        u64 k0 = ((u64)mono32(bf2f(sj.x) + bf2f(si.x)) << 32) | lo;
        u64 k1 = ((u64)mono32(bf2f(sj.y) + bf2f(si.y)) << 32) | lo;
        u64 k2 = ((u64)mono32(bf2f(sj.z) + bf2f(si.z)) << 32) | lo;
        u64 k3 = ((u64)mono32(bf2f(sj.w) + bf2f(si.w)) << 32) | lo;
        if (k0 > c01.x) atomicMax(&slot[0], k0);
        if (k1 > c01.y) atomicMax(&slot[1], k1);
        if (k2 > c23.x) atomicMax(&slot[2], k2);
        if (k3 > c23.y) atomicMax(&slot[3], k3);
    }

    grid_barrier(bar, 2 * GRID);

    // ---------------- phase 3: decode winners -> node_mask ----------------
    for (int t = tid; t < N4; t += stride) {
        u64 m = seg[t];
        if (m) {
            int e = (int)(~(u32)m);
            nm[ei[EE + e]] = 1;     // race-benign: all writers store 1
        }
    }

    grid_barrier(bar, 3 * GRID);

    // ---------------- phase 4: epilogue ----------------
    for (int t = tid; t < EE / 4; t += stride) {
        int4 srcs = ((const int4*)ei)[t];
        int4 dsts = ((const int4*)(ei + EE))[t];
        f32x4 v;
        v.x = (nm[srcs.x] & nm[dsts.x]) ? 1.0f : 0.0f;
        v.y = (nm[srcs.y] & nm[dsts.y]) ? 1.0f : 0.0f;
        v.z = (nm[srcs.z] & nm[dsts.z]) ? 1.0f : 0.0f;
        v.w = (nm[srcs.w] & nm[dsts.w]) ? 1.0f : 0.0f;
        __builtin_nontemporal_store(v, &((f32x4*)(out + EK_OFF))[t]);
    }
    for (int t = tid; t < NN; t += stride) out[NM_OFF + t] = nm[t] ? 1.0f : 0.0f;
    if (tid < 2) out[SL_OFF + tid] = (float)sl[tid];   // 0 and 100000, exact
}

// ---------------------------------------------------------------------------
extern "C" void kernel_launch(void* const* d_in, const int* in_sizes, int n_in,
                              void* d_out, int out_size, void* d_ws, size_t ws_size,
                              hipStream_t stream) {
    // Bind inputs by UNIQUE flat size (permutation-proof):
    const u16* x = nullptr; const int* ei = nullptr; const int* sl = nullptr;
    const u16* W = nullptr; const u16* att = nullptr;
    for (int i = 0; i < n_in; ++i) {
        switch (in_sizes[i]) {
            case NN * CIN:   x   = (const u16*)d_in[i]; break;
            case 2 * EE:     ei  = (const int*)d_in[i]; break;
            case 2:          sl  = (const int*)d_in[i]; break;
            case CIN * CIN:  W   = (const u16*)d_in[i]; break;
            case 256:        att = (const u16*)d_in[i]; break;
            default: break;
        }
    }
    if (!x || !ei || !sl || !W || !att) return;

    float* out = (float*)d_out;             // f32 concat, return order

    // workspace: [bar 64B | seg N4*8 (3.2MB) | nm N*4 (0.4MB) | sjb N*8 | sib N*8]
    // bar..nm is one contiguous memset-zero region (3,600,064 B).
    char* ws = (char*)d_ws;
    u32*     bar = (u32*)    (ws);
    u64*     seg = (u64*)    (ws + 64);
    int*     nm  = (int*)    (ws + 64 + (size_t)N4 * 8);
    ushort4* sjb = (ushort4*)(ws + 64 + (size_t)N4 * 8 + (size_t)NN * 4);
    ushort4* sib = (ushort4*)(ws + 64 + (size_t)N4 * 8 + (size_t)NN * 4 + (size_t)NN * 8);

    // Zero-fills via async memset (graph-capturable; harness itself uses it):
    hipMemsetAsync(ws, 0, 64 + (size_t)N4 * 8 + (size_t)NN * 4, stream);  // bar+seg+nm
    hipMemsetAsync(out, 0, (size_t)EK_OFF * 4, stream);                   // x_out region

    k_fused<<<GRID, BLK, 0, stream>>>(x, ei, sl, W, att, out, sjb, sib, nm, seg, bar);
}